// Round 11
// baseline (1857.558 us; speedup 1.0000x reference)
//
#include <hip/hip_runtime.h>
#include <cstdint>
#include <cstddef>

// ---------------------------------------------------------------------------
// Zeoformer forward. Split-bf16 (hi+lo, 3-product) MFMA GEMMs with
// PRE-SPLIT weights AND pre-split activations (planes produced by producer
// epilogues; GEMM staging = pure short8 copies). Fused q/k/v/skip GEMM.
// Single-pass online-softmax attention, fp32 inputs (round-8 exact math).
// N=20000, E=320000, B=64, F=256, CG=92, NL=4, NP=3.
// (Resubmission: round-10 bench was a broker timeout; kernel never ran.)
// Round-9: bf16 k/v/e attention failed precision 0.375 vs 0.345 (round-8
// fp32 attn passed at 0.0625). This round: revert attn to fp32, keep the
// (numerics-identical) pre-split activation planes for GEMM staging speed.
// ---------------------------------------------------------------------------

#define DEVFN static __device__ __forceinline__

DEVFN float siluf(float x) { return x / (1.f + expf(-x)); }

DEVFN unsigned short f2bf(float x) {
    union { float f; unsigned u; } v; v.f = x;
    return (unsigned short)((v.u + 0x7FFFu + ((v.u >> 16) & 1u)) >> 16);
}
DEVFN float bf2f(unsigned short h) {
    union { unsigned u; float f; } v; v.u = ((unsigned)h) << 16;
    return v.f;
}

typedef __attribute__((ext_vector_type(8))) short bf16x8;
typedef __attribute__((ext_vector_type(4))) float f32x4;

// Output modes for gemm_spp epilogue
#define O_F32    0   // C fp32 (pitch ldc)
#define O_F32P   1   // C fp32 + (P1,P2) hi/lo planes, same pitch ldc
#define O_PPE1   4   // cols<256 -> (P1,P2) planes pitch 256; cols>=256 -> C(x2b)[m*256+c-256]
#define O_PLANES 5   // (P1,P2) planes only, pitch ldc

// ---- split-plane GEMM: all inputs are (hi,lo) bf16 planes -----------------
// Ahi/Alo: [M,lda] shorts (lda = padded K). Whi/Wlo: [OUT,ldw] shorts.
// Tile 128x128, 4 waves (2x2 of 64x64), BK=32, 3 MFMA products (hh, hl, lh).
// LDS pitch 40 shorts -> quarter-wave ds_read_b128 2 lanes/bank (free, m136).
template <int ACT, int OMODE>
__launch_bounds__(256) __global__
void gemm_spp(const short* __restrict__ Ahi, const short* __restrict__ Alo, int lda,
              const short* __restrict__ Whi, const short* __restrict__ Wlo, int ldw,
              const float* __restrict__ bias,
              const float* __restrict__ res, int ldr,
              float* __restrict__ C, short* __restrict__ P1, short* __restrict__ P2,
              int ldc, int M, int OUT, int K)
{
    constexpr int LDP = 40;
    __shared__ short AsH[128 * LDP];
    __shared__ short AsL[128 * LDP];
    __shared__ short WsH[128 * LDP];
    __shared__ short WsL[128 * LDP];
    const int tid = threadIdx.x;
    const int bm = blockIdx.x * 128;
    const int bn = blockIdx.y * 128;
    const int w = tid >> 6, lane = tid & 63;
    const int wm = (w >> 1) * 64, wn = (w & 1) * 64;
    const int lr = lane & 15, lc = lane >> 4;

    f32x4 acc[4][4];
#pragma unroll
    for (int i = 0; i < 4; ++i)
#pragma unroll
        for (int j = 0; j < 4; ++j) acc[i][j] = (f32x4){0.f, 0.f, 0.f, 0.f};

    const int srow = tid & 127;
    const int scol0 = (tid >> 7) * 16;

    for (int k0 = 0; k0 < K; k0 += 32) {
        // ---- stage A planes (pure copies; zero-fill rows >= M)
        {
            int gm = bm + srow;
            if (gm < M) {
                const short* ah = Ahi + (size_t)gm * lda + k0 + scol0;
                const short* al = Alo + (size_t)gm * lda + k0 + scol0;
                *reinterpret_cast<bf16x8*>(&AsH[srow * LDP + scol0])     = *reinterpret_cast<const bf16x8*>(ah);
                *reinterpret_cast<bf16x8*>(&AsH[srow * LDP + scol0 + 8]) = *reinterpret_cast<const bf16x8*>(ah + 8);
                *reinterpret_cast<bf16x8*>(&AsL[srow * LDP + scol0])     = *reinterpret_cast<const bf16x8*>(al);
                *reinterpret_cast<bf16x8*>(&AsL[srow * LDP + scol0 + 8]) = *reinterpret_cast<const bf16x8*>(al + 8);
            } else {
                bf16x8 z = {0, 0, 0, 0, 0, 0, 0, 0};
                *reinterpret_cast<bf16x8*>(&AsH[srow * LDP + scol0])     = z;
                *reinterpret_cast<bf16x8*>(&AsH[srow * LDP + scol0 + 8]) = z;
                *reinterpret_cast<bf16x8*>(&AsL[srow * LDP + scol0])     = z;
                *reinterpret_cast<bf16x8*>(&AsL[srow * LDP + scol0 + 8]) = z;
            }
        }
        // ---- stage W planes
        {
            int go = bn + srow;
            if (go < OUT) {
                const short* wh = Whi + (size_t)go * ldw + k0 + scol0;
                const short* wl = Wlo + (size_t)go * ldw + k0 + scol0;
                *reinterpret_cast<bf16x8*>(&WsH[srow * LDP + scol0])     = *reinterpret_cast<const bf16x8*>(wh);
                *reinterpret_cast<bf16x8*>(&WsH[srow * LDP + scol0 + 8]) = *reinterpret_cast<const bf16x8*>(wh + 8);
                *reinterpret_cast<bf16x8*>(&WsL[srow * LDP + scol0])     = *reinterpret_cast<const bf16x8*>(wl);
                *reinterpret_cast<bf16x8*>(&WsL[srow * LDP + scol0 + 8]) = *reinterpret_cast<const bf16x8*>(wl + 8);
            } else {
                bf16x8 z = {0, 0, 0, 0, 0, 0, 0, 0};
                *reinterpret_cast<bf16x8*>(&WsH[srow * LDP + scol0])     = z;
                *reinterpret_cast<bf16x8*>(&WsH[srow * LDP + scol0 + 8]) = z;
                *reinterpret_cast<bf16x8*>(&WsL[srow * LDP + scol0])     = z;
                *reinterpret_cast<bf16x8*>(&WsL[srow * LDP + scol0 + 8]) = z;
            }
        }
        __syncthreads();

        bf16x8 afh[4], afl[4], bfh[4], bfl[4];
#pragma unroll
        for (int f = 0; f < 4; ++f) {
            afh[f] = *reinterpret_cast<const bf16x8*>(&AsH[(wm + f * 16 + lr) * LDP + lc * 8]);
            afl[f] = *reinterpret_cast<const bf16x8*>(&AsL[(wm + f * 16 + lr) * LDP + lc * 8]);
            bfh[f] = *reinterpret_cast<const bf16x8*>(&WsH[(wn + f * 16 + lr) * LDP + lc * 8]);
            bfl[f] = *reinterpret_cast<const bf16x8*>(&WsL[(wn + f * 16 + lr) * LDP + lc * 8]);
        }
#pragma unroll
        for (int i = 0; i < 4; ++i)
#pragma unroll
            for (int j = 0; j < 4; ++j) {
                acc[i][j] = __builtin_amdgcn_mfma_f32_16x16x32_bf16(afh[i], bfh[j], acc[i][j], 0, 0, 0);
                acc[i][j] = __builtin_amdgcn_mfma_f32_16x16x32_bf16(afh[i], bfl[j], acc[i][j], 0, 0, 0);
                acc[i][j] = __builtin_amdgcn_mfma_f32_16x16x32_bf16(afl[i], bfh[j], acc[i][j], 0, 0, 0);
            }
        __syncthreads();
    }

    // ---- epilogue: C/D layout col=lane&15, row=(lane>>4)*4+reg (m89)
#pragma unroll
    for (int i = 0; i < 4; ++i) {
#pragma unroll
        for (int j = 0; j < 4; ++j) {
            int col = bn + wn + j * 16 + lr;
            if (col >= OUT) continue;
            float bv = bias ? bias[col] : 0.f;
#pragma unroll
            for (int r = 0; r < 4; ++r) {
                int m = bm + wm + i * 16 + lc * 4 + r;
                if (m >= M) continue;
                float v = acc[i][j][r] + bv;
                if (ACT == 1) v = siluf(v);
                if (OMODE == O_F32) {
                    if (res) v += res[(size_t)m * ldr + col];
                    C[(size_t)m * ldc + col] = v;
                } else if (OMODE == O_F32P) {
                    if (res) v += res[(size_t)m * ldr + col];
                    C[(size_t)m * ldc + col] = v;
                    unsigned short hi = f2bf(v);
                    P1[(size_t)m * ldc + col] = (short)hi;
                    P2[(size_t)m * ldc + col] = (short)f2bf(v - bf2f(hi));
                } else if (OMODE == O_PPE1) {
                    if (col < 256) {
                        unsigned short hi = f2bf(v);
                        P1[(size_t)m * 256 + col] = (short)hi;
                        P2[(size_t)m * 256 + col] = (short)f2bf(v - bf2f(hi));
                    } else {
                        C[(size_t)m * 256 + (col - 256)] = v;
                    }
                } else {  // O_PLANES
                    unsigned short hi = f2bf(v);
                    P1[(size_t)m * ldc + col] = (short)hi;
                    P2[(size_t)m * ldc + col] = (short)f2bf(v - bf2f(hi));
                }
            }
        }
    }
}

// ------------------------- fp32 GEMM (head only) ---------------------------
template <int BM, int BN, int TM, int TN, int ACT>
__launch_bounds__(256) __global__
void gemm_nt(const float* __restrict__ A, int lda,
             const float* __restrict__ W,
             const float* __restrict__ bias,
             const float* __restrict__ res, int ldr,
             float* __restrict__ C, int ldc,
             int M, int K, int OUT)
{
    constexpr int BK = 16;
    __shared__ alignas(16) float As[BK][BM];
    __shared__ alignas(16) float Bs[BK][BN];
    const int tid = threadIdx.x;
    const int bm = blockIdx.x * BM;
    const int bn = blockIdx.y * BN;
    const int tr = (tid >> 4) * TM;
    const int tc = (tid & 15) * TN;

    float acc[TM][TN];
#pragma unroll
    for (int i = 0; i < TM; ++i)
#pragma unroll
        for (int j = 0; j < TN; ++j) acc[i][j] = 0.f;

    for (int k0 = 0; k0 < K; k0 += BK) {
#pragma unroll
        for (int it = 0; it < BM / 64; ++it) {
            int idx = tid + it * 256;
            int m = idx >> 2, kq = idx & 3;
            int gm = bm + m, gk = k0 + kq * 4;
            float t[4] = {0.f, 0.f, 0.f, 0.f};
            if (gm < M) {
#pragma unroll
                for (int j = 0; j < 4; ++j)
                    if (gk + j < K) t[j] = A[(size_t)gm * lda + gk + j];
            }
            As[kq * 4 + 0][m] = t[0];
            As[kq * 4 + 1][m] = t[1];
            As[kq * 4 + 2][m] = t[2];
            As[kq * 4 + 3][m] = t[3];
        }
#pragma unroll
        for (int it = 0; it < BN / 64; ++it) {
            int idx = tid + it * 256;
            int o = idx >> 2, kq = idx & 3;
            int go = bn + o, gk = k0 + kq * 4;
            float t[4] = {0.f, 0.f, 0.f, 0.f};
            if (go < OUT) {
#pragma unroll
                for (int j = 0; j < 4; ++j)
                    if (gk + j < K) t[j] = W[(size_t)go * K + gk + j];
            }
            Bs[kq * 4 + 0][o] = t[0];
            Bs[kq * 4 + 1][o] = t[1];
            Bs[kq * 4 + 2][o] = t[2];
            Bs[kq * 4 + 3][o] = t[3];
        }
        __syncthreads();
#pragma unroll
        for (int kk = 0; kk < BK; ++kk) {
            float a[TM], b[TN];
#pragma unroll
            for (int p = 0; p < TM; ++p) a[p] = As[kk][tr + p];
#pragma unroll
            for (int p = 0; p < TN; ++p) b[p] = Bs[kk][tc + p];
#pragma unroll
            for (int i = 0; i < TM; ++i)
#pragma unroll
                for (int j = 0; j < TN; ++j) acc[i][j] += a[i] * b[j];
        }
        __syncthreads();
    }

#pragma unroll
    for (int i = 0; i < TM; ++i) {
        int m = bm + tr + i;
        if (m >= M) continue;
#pragma unroll
        for (int j = 0; j < TN; ++j) {
            int o = bn + tc + j;
            if (o >= OUT) continue;
            float v = acc[i][j];
            if (bias) v += bias[o];
            if (ACT == 1) v = siluf(v);
            if (res) v += res[(size_t)m * ldr + o];
            C[(size_t)m * ldc + o] = v;
        }
    }
}

// ------------------------- weight prep kernels -----------------------------
__global__ void split_w_k(const float* __restrict__ src, short* __restrict__ dhi,
                          short* __restrict__ dlo, int OUT, int K, int Kp)
{
    int idx = blockIdx.x * blockDim.x + threadIdx.x;
    if (idx >= OUT * Kp) return;
    int row = idx / Kp, col = idx - row * Kp;
    float v = (col < K) ? src[(size_t)row * K + col] : 0.f;
    unsigned short hi = f2bf(v);
    dhi[idx] = (short)hi;
    dlo[idx] = (short)f2bf(v - bf2f(hi));
}

__global__ void stack_qkvs_w_k(const float* __restrict__ Wq, const float* __restrict__ Wk,
                               const float* __restrict__ Wv, const float* __restrict__ Ws,
                               short* __restrict__ dhi, short* __restrict__ dlo, int total)
{
    int idx = blockIdx.x * blockDim.x + threadIdx.x;
    if (idx >= total) return;
    int col = idx & 255;
    int row = (idx >> 8) & 1023;
    int layer = idx >> 18;
    int s2 = row >> 8;
    const float* s = (s2 == 0) ? Wq : ((s2 == 1) ? Wk : ((s2 == 2) ? Wv : Ws));
    float v = s[(size_t)layer * 65536 + (size_t)(row & 255) * 256 + col];
    unsigned short hi = f2bf(v);
    dhi[idx] = (short)hi;
    dlo[idx] = (short)f2bf(v - bf2f(hi));
}

__global__ void stack_qkvs_b_k(const float* __restrict__ bq, const float* __restrict__ bk,
                               const float* __restrict__ bv, const float* __restrict__ bs,
                               float* __restrict__ dst, int total)
{
    int idx = blockIdx.x * blockDim.x + threadIdx.x;
    if (idx >= total) return;
    int r = idx & 1023, layer = idx >> 10;
    int s2 = r >> 8;
    const float* s = (s2 == 0) ? bq : ((s2 == 1) ? bk : ((s2 == 2) ? bv : bs));
    dst[idx] = s[layer * 256 + (r & 255)];
}

// ------------------------- producer kernels (emit planes) -------------------
__global__ void node_prep_k(const float* __restrict__ x,
                            short* __restrict__ fxHi, short* __restrict__ fxLo,
                            short* __restrict__ pxHi, short* __restrict__ pxLo, int n96)
{
    int idx = blockIdx.x * blockDim.x + threadIdx.x;
    if (idx >= n96) return;
    int n = idx / 96, c = idx - n * 96;
    float fv = 0.f, pv = 0.f;
    if (c < 92) {
        float v = x[(size_t)n * 92 + c];
        fv = floorf(v);
        pv = (v - truncf(v)) * 1000.f;
    }
    unsigned short h1 = f2bf(fv);
    fxHi[idx] = (short)h1; fxLo[idx] = (short)f2bf(fv - bf2f(h1));
    unsigned short h2 = f2bf(pv);
    pxHi[idx] = (short)h2; pxLo[idx] = (short)f2bf(pv - bf2f(h2));
}

__global__ void table_rbf_k(short* __restrict__ dhi, short* __restrict__ dlo,
                            int T, float dmin, float step)
{
    int idx = blockIdx.x * blockDim.x + threadIdx.x;   // T*64 threads
    if (idx >= T * 64) return;
    int t = idx >> 6, j4 = (idx & 63) * 4;
    float dv = dmin + step * (float)t;
    short h4[4], l4[4];
#pragma unroll
    for (int j = 0; j < 4; ++j) {
        float c = -6.f + 6.f * (float)(j4 + j) * (1.f / 255.f);
        float u = dv - c;
        float r = expf(-42.5f * u * u);
        unsigned short hi = f2bf(r);
        h4[j] = (short)hi;
        l4[j] = (short)f2bf(r - bf2f(hi));
    }
    *reinterpret_cast<short4*>(dhi + (size_t)t * 256 + j4) = *reinterpret_cast<short4*>(h4);
    *reinterpret_cast<short4*>(dlo + (size_t)t * 256 + j4) = *reinterpret_cast<short4*>(l4);
}

__global__ void edge_prep_k(const float* __restrict__ ea, int* __restrict__ i0,
                            float* __restrict__ fr, int E, float dmin, float invstep, int T)
{
    int i = blockIdx.x * blockDim.x + threadIdx.x;
    if (i < E) {
        float a = ea[(size_t)i * 3], b = ea[(size_t)i * 3 + 1], c = ea[(size_t)i * 3 + 2];
        float d = -1.f / sqrtf(a * a + b * b + c * c);
        float u = (d - dmin) * invstep;
        u = fminf(fmaxf(u, 0.f), (float)(T - 1) - 1e-3f);
        int t0 = (int)u;
        i0[i] = t0;
        fr[i] = u - (float)t0;
    }
}

__global__ void ppe_prep_k(float* __restrict__ ppe, const float* __restrict__ h,
                           const float* __restrict__ pg, const float* __restrict__ pbeta,
                           short* __restrict__ s1Hi, short* __restrict__ s1Lo, int n)
{
    int i = blockIdx.x * blockDim.x + threadIdx.x;
    if (i < n) {
        float adj = ppe[i] + h[i];
        ppe[i] = adj;
        int f = i & 255;
        float bn = adj * pg[f] + pbeta[f];
        unsigned short hi = f2bf(bn);
        s1Hi[i] = (short)hi;
        s1Lo[i] = (short)f2bf(bn - bf2f(hi));
    }
}

__global__ void gate_k(const float* __restrict__ x1, const float* __restrict__ x2b,
                       short* __restrict__ s3Hi, short* __restrict__ s3Lo, int n)
{
    int i = blockIdx.x * blockDim.x + threadIdx.x;
    if (i < n) {
        float x2 = x2b[i];
        float ge = 0.5f * x2 * (1.f + erff(x2 * 0.70710678118654752f));
        float g = x1[i] * ge;
        unsigned short hi = f2bf(g);
        s3Hi[i] = (short)hi;
        s3Lo[i] = (short)f2bf(g - bf2f(hi));
    }
}

// ------------------------- edge sort by dst (counting sort) ----------------
__global__ void hist_k(const int* __restrict__ dst, int* __restrict__ deg, int E)
{
    int i = blockIdx.x * blockDim.x + threadIdx.x;
    if (i < E) atomicAdd(&deg[dst[i]], 1);
}

__global__ void scan_k(const int* __restrict__ deg, int* __restrict__ off, int n)
{
    __shared__ int buf[1024];
    __shared__ int carry;
    const int t = threadIdx.x;
    if (t == 0) carry = 0;
    __syncthreads();
    for (int base = 0; base < n; base += 1024) {
        int i = base + t;
        int v = (i < n) ? deg[i] : 0;
        buf[t] = v;
        __syncthreads();
        for (int s = 1; s < 1024; s <<= 1) {
            int add = (t >= s) ? buf[t - s] : 0;
            __syncthreads();
            buf[t] += add;
            __syncthreads();
        }
        if (i < n) off[i] = carry + buf[t] - v;
        __syncthreads();
        if (t == 0) carry += buf[1023];
        __syncthreads();
    }
    if (t == 0) off[n] = carry;
}

__global__ void copy_int_k(const int* __restrict__ a, int* __restrict__ b, int n)
{
    int i = blockIdx.x * blockDim.x + threadIdx.x;
    if (i < n) b[i] = a[i];
}

__global__ void scatter_k(const int* __restrict__ dst, int* __restrict__ cursor,
                          int* __restrict__ esort, int E)
{
    int i = blockIdx.x * blockDim.x + threadIdx.x;
    if (i < E) {
        int p = atomicAdd(&cursor[dst[i]], 1);
        esort[p] = i;
    }
}

// ---------------- single-pass online-softmax attention (fp32, round-8) -----
// qkvs: [N,1024] fp32 = q|k|v|skip. etab: [T,256] fp32.
__launch_bounds__(256) __global__
void attn_fused_k(const float* __restrict__ qkvs, const float* __restrict__ etab,
                  const int* __restrict__ ei0, const float* __restrict__ efr,
                  const int* __restrict__ src, const int* __restrict__ esort,
                  const int* __restrict__ off, float* __restrict__ hn, int Nn)
{
    int node = blockIdx.x * 4 + (threadIdx.x >> 6);
    if (node >= Nn) return;
    int lane = threadIdx.x & 63;
    int lo = off[node], hi = off[node + 1];

    const float* qrow = qkvs + (size_t)node * 1024;
    float4 qv = *reinterpret_cast<const float4*>(qrow + lane * 4);
    float4 sk = *reinterpret_cast<const float4*>(qrow + 768 + lane * 4);

    float m = -3.4e38f, den = 0.f;
    float ax = 0.f, ay = 0.f, az = 0.f, aw = 0.f;

    for (int jj = lo; jj < hi; ++jj) {
        int eid = esort[jj];
        int sp = src[eid];
        int t0 = ei0[eid];
        float f = efr[eid];
        const float* srow = qkvs + (size_t)sp * 1024;
        float4 kv = *reinterpret_cast<const float4*>(srow + 256 + lane * 4);
        float4 e0 = *reinterpret_cast<const float4*>(etab + (size_t)t0 * 256 + lane * 4);
        float4 e1 = *reinterpret_cast<const float4*>(etab + (size_t)(t0 + 1) * 256 + lane * 4);
        float ex0 = e0.x + f * (e1.x - e0.x);
        float ex1 = e0.y + f * (e1.y - e0.y);
        float ex2 = e0.z + f * (e1.z - e0.z);
        float ex3 = e0.w + f * (e1.w - e0.w);
        float p = qv.x * (kv.x + ex0) + qv.y * (kv.y + ex1) +
                  qv.z * (kv.z + ex2) + qv.w * (kv.w + ex3);
#pragma unroll
        for (int s = 32; s; s >>= 1) p += __shfl_xor(p, s, 64);
        p *= 0.0625f;                                   // /sqrt(F)=16 exactly
        float4 vv = *reinterpret_cast<const float4*>(srow + 512 + lane * 4);
        float vx0 = vv.x + ex0, vx1 = vv.y + ex1, vx2 = vv.z + ex2, vx3 = vv.w + ex3;
        if (p > m) {                                    // wave-uniform branch
            float sc = expf(m - p);                     // first iter: exp(-inf)=0
            den = den * sc + 1.f;
            ax = ax * sc + vx0;
            ay = ay * sc + vx1;
            az = az * sc + vx2;
            aw = aw * sc + vx3;
            m = p;
        } else {
            float wgt = expf(p - m);
            den += wgt;
            ax += wgt * vx0;
            ay += wgt * vx1;
            az += wgt * vx2;
            aw += wgt * vx3;
        }
    }
    float inv = (hi > lo) ? 1.f / den : 0.f;
    float4 o = {sk.x + ax * inv, sk.y + ay * inv, sk.z + az * inv, sk.w + aw * inv};
    *reinterpret_cast<float4*>(hn + (size_t)node * 256 + lane * 4) = o;
}

// ------------------------- pooling / output ---------------------------------
__launch_bounds__(256) __global__
void pool_mean_k(const float* __restrict__ h, const int* __restrict__ batch,
                 float* __restrict__ tot, int Nn)
{
    int g = blockIdx.x;
    __shared__ int sl, sh;
    if (threadIdx.x == 0) {
        int lo = 0, hi = Nn;
        while (lo < hi) { int mid = (lo + hi) >> 1; if (batch[mid] < g) lo = mid + 1; else hi = mid; }
        sl = lo;
        lo = 0; hi = Nn;
        while (lo < hi) { int mid = (lo + hi) >> 1; if (batch[mid] < g + 1) lo = mid + 1; else hi = mid; }
        sh = lo;
    }
    __syncthreads();
    float acc = 0.f;
    for (int n = sl; n < sh; ++n) acc += h[(size_t)n * 256 + threadIdx.x];
    float c = (float)(sh - sl);
    if (c < 1.f) c = 1.f;
    tot[(size_t)g * 256 + threadIdx.x] = acc / c;
}

__launch_bounds__(256) __global__
void out_k(const float* __restrict__ crystal, const float* __restrict__ oW,
           const float* __restrict__ ob, const float* __restrict__ nosda,
           float* __restrict__ out, int Bn)
{
    int b = blockIdx.x;
    __shared__ float red[256];
    float p = crystal[(size_t)b * 256 + threadIdx.x] * oW[threadIdx.x];
    red[threadIdx.x] = p;
    __syncthreads();
    for (int s = 128; s; s >>= 1) {
        if (threadIdx.x < s) red[threadIdx.x] += red[threadIdx.x + s];
        __syncthreads();
    }
    if (threadIdx.x == 0) out[b] = (red[0] + ob[0]) / nosda[b];
}

// ---------------------------------------------------------------------------
extern "C" void kernel_launch(void* const* d_in, const int* in_sizes, int n_in,
                              void* d_out, int out_size, void* d_ws, size_t ws_size,
                              hipStream_t stream)
{
    const float* x     = (const float*)d_in[0];
    const int*   ei    = (const int*)d_in[1];
    const float* ea    = (const float*)d_in[2];
    const int*   batch = (const int*)d_in[3];
    const float* nosda = (const float*)d_in[4];
    const float* ae_W1 = (const float*)d_in[5];
    const float* ae_b1 = (const float*)d_in[6];
    const float* ae_W2 = (const float*)d_in[7];
    const float* ae_b2 = (const float*)d_in[8];
    const float* ee_W  = (const float*)d_in[9];
    const float* ee_b  = (const float*)d_in[10];
    const float* pe_W  = (const float*)d_in[11];
    const float* pe_b  = (const float*)d_in[12];
    const float* Wq    = (const float*)d_in[13];
    const float* bq    = (const float*)d_in[14];
    const float* Wk    = (const float*)d_in[15];
    const float* bk    = (const float*)d_in[16];
    const float* Wv    = (const float*)d_in[17];
    const float* bv    = (const float*)d_in[18];
    const float* We    = (const float*)d_in[19];
    const float* be    = (const float*)d_in[20];
    const float* Ws    = (const float*)d_in[21];
    const float* bs    = (const float*)d_in[22];
    const float* pW1   = (const float*)d_in[23];
    const float* pb1   = (const float*)d_in[24];
    const float* pW2   = (const float*)d_in[25];
    const float* pb2   = (const float*)d_in[26];
    const float* pW3   = (const float*)d_in[27];
    const float* pb3   = (const float*)d_in[28];
    const float* pg    = (const float*)d_in[29];
    const float* pbeta = (const float*)d_in[30];
    const float* fc_W  = (const float*)d_in[31];
    const float* fc_b  = (const float*)d_in[32];
    const float* out_W = (const float*)d_in[33];
    const float* out_b = (const float*)d_in[34];

    const int CG = 92, F = 256;
    const int N = in_sizes[0] / CG;
    const int E = in_sizes[1] / 2;
    const int B = in_sizes[4];
    const int T = 4096;
    const float DMIN = -8.f, DMAX = 0.f;
    const float STEP = (DMAX - DMIN) / (float)(T - 1);
    const int* src  = ei;
    const int* dstp = ei + E;

    // ---- workspace carve-up (~214 MB; proven-safe budget ~256 MB) ----------
    float* w = (float*)d_ws;
    auto take = [&](size_t n) { float* p = w; w += n; return p; };
    auto takeS = [&](size_t nshorts) { short* p = (short*)w; w += (nshorts + 1) / 2; return p; };
    const size_t NF = (size_t)N * F;
    float* hb0  = take(NF);
    float* hb1  = take(NF);
    float* ppeb = take(NF);
    short* hHi  = takeS(NF);           // planes of current h (qkvs GEMM input)
    short* hLo  = takeS(NF);
    short* s1Hi = takeS(NF);           // bn planes (p1 GEMM input)
    short* s1Lo = takeS(NF);
    float* etab = take((size_t)4 * T * F);     // fp32 e-tables [4,T,256]
    float* arena = take((size_t)N * 1024);     // time-shared (T1/T2/T3)
    float* efr  = take(E);
    float* totb = take((size_t)B * F);
    float* cryb = take((size_t)B * F);
    float* bstk = take(4 * 1024);
    // weight planes
    short* qwHi = takeS((size_t)4 * 1024 * 256);
    short* qwLo = takeS((size_t)4 * 1024 * 256);
    short* eeHi = takeS((size_t)256 * 256);
    short* eeLo = takeS((size_t)256 * 256);
    short* weHi = takeS((size_t)4 * 256 * 256);
    short* weLo = takeS((size_t)4 * 256 * 256);
    short* a1Hi = takeS((size_t)256 * 96);
    short* a1Lo = takeS((size_t)256 * 96);
    short* a2Hi = takeS((size_t)256 * 256);
    short* a2Lo = takeS((size_t)256 * 256);
    short* peHi = takeS((size_t)256 * 96);
    short* peLo = takeS((size_t)256 * 96);
    short* p1Hi = takeS((size_t)3 * 512 * 256);
    short* p1Lo = takeS((size_t)3 * 512 * 256);
    short* p2Hi = takeS((size_t)3 * 256 * 256);
    short* p2Lo = takeS((size_t)3 * 256 * 256);
    short* p3Hi = takeS((size_t)3 * 256 * 256);
    short* p3Lo = takeS((size_t)3 * 256 * 256);
    int* ei0    = (int*)w; w += E;
    int* deg    = (int*)w; w += N;
    int* offb   = (int*)w; w += (N + 1);
    int* curb   = (int*)w; w += N;
    int* esort  = (int*)w; w += E;
    size_t need = (size_t)((char*)w - (char*)d_ws);
    if (need > ws_size) return;               // fail loud, not a fault
    (void)n_in; (void)out_size;

    // Arena tenants (disjoint lifetimes):
    // T1 (pre-loop): fx/px planes [N,96], rb/ef planes [T,256], emb planes [N,256]
    short* fxHi = (short*)arena;
    short* fxLo = fxHi + (size_t)N * 96;
    short* pxHi = fxLo + (size_t)N * 96;
    short* pxLo = pxHi + (size_t)N * 96;
    short* rbHi = pxLo + (size_t)N * 96;
    short* rbLo = rbHi + (size_t)T * 256;
    short* efHi = rbLo + (size_t)T * 256;
    short* efLo = efHi + (size_t)T * 256;
    short* embHi = efLo + (size_t)T * 256;
    short* embLo = embHi + NF;
    // T2 (attn phase): qkvs fp32 [N,1024] = whole arena
    float* qkvs = arena;
    // T3 (ppe phase): a2b1 planes [N,256] + x2b fp32 + s2b fp32 + s3 planes
    short* a2b1Hi = (short*)arena;
    short* a2b1Lo = a2b1Hi + NF;
    float* x2b = arena + NF;          // 2*NF shorts == NF floats
    float* s2b = x2b + NF;
    short* s3Hi = (short*)(s2b + NF);
    short* s3Lo = s3Hi + NF;

    dim3 blk(256);
    auto g1 = [](int n) { return dim3((n + 255) / 256); };

    // ---- prep + weight splitting
    node_prep_k<<<g1(N * 96), blk, 0, stream>>>(x, fxHi, fxLo, pxHi, pxLo, N * 96);
    edge_prep_k<<<g1(E), blk, 0, stream>>>(ea, ei0, efr, E, DMIN, 1.f / STEP, T);
    table_rbf_k<<<g1(T * 64), blk, 0, stream>>>(rbHi, rbLo, T, DMIN, STEP);

    stack_qkvs_w_k<<<g1(4 * 1024 * 256), blk, 0, stream>>>(Wq, Wk, Wv, Ws, qwHi, qwLo, 4 * 1024 * 256);
    stack_qkvs_b_k<<<g1(4 * 1024), blk, 0, stream>>>(bq, bk, bv, bs, bstk, 4 * 1024);
    split_w_k<<<g1(256 * 256), blk, 0, stream>>>(ee_W, eeHi, eeLo, 256, 256, 256);
    split_w_k<<<g1(4 * 256 * 256), blk, 0, stream>>>(We, weHi, weLo, 1024, 256, 256);
    split_w_k<<<g1(256 * 96), blk, 0, stream>>>(ae_W1, a1Hi, a1Lo, 256, 92, 96);
    split_w_k<<<g1(256 * 256), blk, 0, stream>>>(ae_W2, a2Hi, a2Lo, 256, 256, 256);
    split_w_k<<<g1(256 * 96), blk, 0, stream>>>(pe_W, peHi, peLo, 256, 92, 96);
    split_w_k<<<g1(3 * 512 * 256), blk, 0, stream>>>(pW1, p1Hi, p1Lo, 1536, 256, 256);
    split_w_k<<<g1(3 * 256 * 256), blk, 0, stream>>>(pW2, p2Hi, p2Lo, 768, 256, 256);
    split_w_k<<<g1(3 * 256 * 256), blk, 0, stream>>>(pW3, p3Hi, p3Lo, 768, 256, 256);

    // ---- tables: ef = silu(rbf@eeW) (planes); e_i = ef@We_i (fp32)
    {
        dim3 grid((T + 127) / 128, 2);
        gemm_spp<1, O_PLANES><<<grid, blk, 0, stream>>>(rbHi, rbLo, 256, eeHi, eeLo, 256,
                                                        ee_b, nullptr, 0, nullptr, efHi, efLo, 256, T, 256, 256);
        for (int i = 0; i < 4; ++i)
            gemm_spp<0, O_F32><<<grid, blk, 0, stream>>>(efHi, efLo, 256,
                weHi + (size_t)i * 65536, weLo + (size_t)i * 65536, 256,
                be + (size_t)i * F, nullptr, 0, etab + (size_t)i * T * F, nullptr, nullptr, 256, T, 256, 256);
    }

    // ---- embeddings
    {
        dim3 grid((N + 127) / 128, 2);
        gemm_spp<1, O_PLANES><<<grid, blk, 0, stream>>>(fxHi, fxLo, 96, a1Hi, a1Lo, 96,
                                                        ae_b1, nullptr, 0, nullptr, embHi, embLo, 256, N, 256, 96);
        gemm_spp<0, O_F32P><<<grid, blk, 0, stream>>>(embHi, embLo, 256, a2Hi, a2Lo, 256,
                                                      ae_b2, nullptr, 0, hb0, hHi, hLo, 256, N, 256, 256);
        gemm_spp<0, O_F32><<<grid, blk, 0, stream>>>(pxHi, pxLo, 96, peHi, peLo, 96,
                                                     pe_b, nullptr, 0, ppeb, nullptr, nullptr, 256, N, 256, 96);
    }

    // ---- counting-sort edges by dst
    hipMemsetAsync(deg, 0, (size_t)N * sizeof(int), stream);
    hist_k<<<g1(E), blk, 0, stream>>>(dstp, deg, E);
    scan_k<<<1, 1024, 0, stream>>>(deg, offb, N);
    copy_int_k<<<g1(N), blk, 0, stream>>>(offb, curb, N);
    scatter_k<<<g1(E), blk, 0, stream>>>(dstp, curb, esort, E);

    float* h  = hb0;
    float* hn = hb1;
    for (int i = 0; i < 4; ++i) {
        // fused q|k|v|skip GEMM from h planes -> qkvs fp32 [N,1024]  (T2)
        {
            dim3 grid((N + 127) / 128, 8);
            gemm_spp<0, O_F32><<<grid, blk, 0, stream>>>(hHi, hLo, 256,
                qwHi + (size_t)i * 262144, qwLo + (size_t)i * 262144, 256,
                bstk + (size_t)i * 1024, nullptr, 0, qkvs, nullptr, nullptr, 1024, N, 1024, 256);
        }

        attn_fused_k<<<dim3((N + 3) / 4), blk, 0, stream>>>(
            qkvs, etab + (size_t)i * T * F, ei0, efr, src, esort, offb, hn, N);
        { float* t = h; h = hn; hn = t; }

        if (i < 3) {                                     // ppe phase (T3)
            ppe_prep_k<<<g1(N * F), blk, 0, stream>>>(ppeb, h, pg + (size_t)i * F, pbeta + (size_t)i * F,
                                                      s1Hi, s1Lo, N * F);
            {
                dim3 grid((N + 127) / 128, 4);
                gemm_spp<0, O_PPE1><<<grid, blk, 0, stream>>>(s1Hi, s1Lo, 256,
                    p1Hi + (size_t)i * 131072, p1Lo + (size_t)i * 131072, 256,
                    pb1 + (size_t)i * 512, nullptr, 0, x2b, a2b1Hi, a2b1Lo, 0, N, 512, 256);
            }
            {
                dim3 grid((N + 127) / 128, 2);
                gemm_spp<0, O_F32><<<grid, blk, 0, stream>>>(a2b1Hi, a2b1Lo, 256,
                    p2Hi + (size_t)i * 65536, p2Lo + (size_t)i * 65536, 256,
                    pb2 + (size_t)i * F, nullptr, 0, s2b, nullptr, nullptr, 256, N, 256, 256);
            }
            gate_k<<<g1(N * F), blk, 0, stream>>>(s2b, x2b, s3Hi, s3Lo, N * F);
            {
                dim3 grid((N + 127) / 128, 2);
                gemm_spp<0, O_F32P><<<grid, blk, 0, stream>>>(s3Hi, s3Lo, 256,
                    p3Hi + (size_t)i * 65536, p3Lo + (size_t)i * 65536, 256,
                    pb3 + (size_t)i * F, h, 256, hn, hHi, hLo, 256, N, 256, 256);
            }
            { float* t = h; h = hn; hn = t; }
        }
    }

    // ---- pooling + head (fp32)
    pool_mean_k<<<dim3(B), blk, 0, stream>>>(h, batch, totb, N);
    {
        dim3 grid((B + 63) / 64, (F + 63) / 64);
        gemm_nt<64, 64, 4, 4, 1><<<grid, blk, 0, stream>>>(totb, F, fc_W, fc_b, totb, F, cryb, F, B, F, F);
    }
    out_k<<<dim3(B), blk, 0, stream>>>(cryb, out_W, out_b, nosda, (float*)d_out, B);
}

// Round 12
// 1775.010 us; speedup vs baseline: 1.0465x; 1.0465x over previous
//
#include <hip/hip_runtime.h>
#include <cstdint>
#include <cstddef>

// ---------------------------------------------------------------------------
// Zeoformer forward. Split-bf16 (hi+lo, 3-product) MFMA GEMMs, pre-split
// weight+activation planes. Fused q/k/v/skip GEMM. Single-pass online-softmax
// attention (fp32) with 2-WAY INTERLEAVED edge states + fused ppe update.
// Gate fused into p2 epilogue. 4 e-table GEMMs stacked into one OUT=1024.
// N=20000, E=320000, B=64, F=256, CG=92, NL=4, NP=3.
// Round-11: 1857us, absmax 0.0625. GEMM fleet latency/occupancy-bound (not
// staging-bound); attn latency-bound (42% HBM, 23% VALU, serial edge chain).
// This round: MLP in attn edge loop + kernel fusion to cut launches/traffic.
// ---------------------------------------------------------------------------

#define DEVFN static __device__ __forceinline__

DEVFN float siluf(float x) { return x / (1.f + expf(-x)); }

DEVFN unsigned short f2bf(float x) {
    union { float f; unsigned u; } v; v.f = x;
    return (unsigned short)((v.u + 0x7FFFu + ((v.u >> 16) & 1u)) >> 16);
}
DEVFN float bf2f(unsigned short h) {
    union { unsigned u; float f; } v; v.u = ((unsigned)h) << 16;
    return v.f;
}

typedef __attribute__((ext_vector_type(8))) short bf16x8;
typedef __attribute__((ext_vector_type(4))) float f32x4;

// Output modes for gemm_spp epilogue
#define O_F32    0   // C fp32 (pitch ldc)
#define O_F32P   1   // C fp32 + (P1,P2) hi/lo planes, same pitch ldc
#define O_PPE1   4   // cols<256 -> (P1,P2) planes pitch 256; cols>=256 -> C(x2b)[m*256+c-256]
#define O_PLANES 5   // (P1,P2) planes only, pitch ldc
#define O_GATE   6   // g = v * gelu(res[m*ldr+col]); (P1,P2) planes pitch ldc

// ---- split-plane GEMM: all inputs are (hi,lo) bf16 planes -----------------
// Tile 128x128, 4 waves (2x2 of 64x64), BK=32, 3 MFMA products (hh, hl, lh).
// LDS pitch 40 shorts -> quarter-wave ds_read_b128 2 lanes/bank (free, m136).
template <int ACT, int OMODE>
__launch_bounds__(256) __global__
void gemm_spp(const short* __restrict__ Ahi, const short* __restrict__ Alo, int lda,
              const short* __restrict__ Whi, const short* __restrict__ Wlo, int ldw,
              const float* __restrict__ bias,
              const float* __restrict__ res, int ldr,
              float* __restrict__ C, short* __restrict__ P1, short* __restrict__ P2,
              int ldc, int M, int OUT, int K)
{
    constexpr int LDP = 40;
    __shared__ short AsH[128 * LDP];
    __shared__ short AsL[128 * LDP];
    __shared__ short WsH[128 * LDP];
    __shared__ short WsL[128 * LDP];
    const int tid = threadIdx.x;
    const int bm = blockIdx.x * 128;
    const int bn = blockIdx.y * 128;
    const int w = tid >> 6, lane = tid & 63;
    const int wm = (w >> 1) * 64, wn = (w & 1) * 64;
    const int lr = lane & 15, lc = lane >> 4;

    f32x4 acc[4][4];
#pragma unroll
    for (int i = 0; i < 4; ++i)
#pragma unroll
        for (int j = 0; j < 4; ++j) acc[i][j] = (f32x4){0.f, 0.f, 0.f, 0.f};

    const int srow = tid & 127;
    const int scol0 = (tid >> 7) * 16;

    for (int k0 = 0; k0 < K; k0 += 32) {
        {
            int gm = bm + srow;
            if (gm < M) {
                const short* ah = Ahi + (size_t)gm * lda + k0 + scol0;
                const short* al = Alo + (size_t)gm * lda + k0 + scol0;
                *reinterpret_cast<bf16x8*>(&AsH[srow * LDP + scol0])     = *reinterpret_cast<const bf16x8*>(ah);
                *reinterpret_cast<bf16x8*>(&AsH[srow * LDP + scol0 + 8]) = *reinterpret_cast<const bf16x8*>(ah + 8);
                *reinterpret_cast<bf16x8*>(&AsL[srow * LDP + scol0])     = *reinterpret_cast<const bf16x8*>(al);
                *reinterpret_cast<bf16x8*>(&AsL[srow * LDP + scol0 + 8]) = *reinterpret_cast<const bf16x8*>(al + 8);
            } else {
                bf16x8 z = {0, 0, 0, 0, 0, 0, 0, 0};
                *reinterpret_cast<bf16x8*>(&AsH[srow * LDP + scol0])     = z;
                *reinterpret_cast<bf16x8*>(&AsH[srow * LDP + scol0 + 8]) = z;
                *reinterpret_cast<bf16x8*>(&AsL[srow * LDP + scol0])     = z;
                *reinterpret_cast<bf16x8*>(&AsL[srow * LDP + scol0 + 8]) = z;
            }
        }
        {
            int go = bn + srow;
            if (go < OUT) {
                const short* wh = Whi + (size_t)go * ldw + k0 + scol0;
                const short* wl = Wlo + (size_t)go * ldw + k0 + scol0;
                *reinterpret_cast<bf16x8*>(&WsH[srow * LDP + scol0])     = *reinterpret_cast<const bf16x8*>(wh);
                *reinterpret_cast<bf16x8*>(&WsH[srow * LDP + scol0 + 8]) = *reinterpret_cast<const bf16x8*>(wh + 8);
                *reinterpret_cast<bf16x8*>(&WsL[srow * LDP + scol0])     = *reinterpret_cast<const bf16x8*>(wl);
                *reinterpret_cast<bf16x8*>(&WsL[srow * LDP + scol0 + 8]) = *reinterpret_cast<const bf16x8*>(wl + 8);
            } else {
                bf16x8 z = {0, 0, 0, 0, 0, 0, 0, 0};
                *reinterpret_cast<bf16x8*>(&WsH[srow * LDP + scol0])     = z;
                *reinterpret_cast<bf16x8*>(&WsH[srow * LDP + scol0 + 8]) = z;
                *reinterpret_cast<bf16x8*>(&WsL[srow * LDP + scol0])     = z;
                *reinterpret_cast<bf16x8*>(&WsL[srow * LDP + scol0 + 8]) = z;
            }
        }
        __syncthreads();

        bf16x8 afh[4], afl[4], bfh[4], bfl[4];
#pragma unroll
        for (int f = 0; f < 4; ++f) {
            afh[f] = *reinterpret_cast<const bf16x8*>(&AsH[(wm + f * 16 + lr) * LDP + lc * 8]);
            afl[f] = *reinterpret_cast<const bf16x8*>(&AsL[(wm + f * 16 + lr) * LDP + lc * 8]);
            bfh[f] = *reinterpret_cast<const bf16x8*>(&WsH[(wn + f * 16 + lr) * LDP + lc * 8]);
            bfl[f] = *reinterpret_cast<const bf16x8*>(&WsL[(wn + f * 16 + lr) * LDP + lc * 8]);
        }
#pragma unroll
        for (int i = 0; i < 4; ++i)
#pragma unroll
            for (int j = 0; j < 4; ++j) {
                acc[i][j] = __builtin_amdgcn_mfma_f32_16x16x32_bf16(afh[i], bfh[j], acc[i][j], 0, 0, 0);
                acc[i][j] = __builtin_amdgcn_mfma_f32_16x16x32_bf16(afh[i], bfl[j], acc[i][j], 0, 0, 0);
                acc[i][j] = __builtin_amdgcn_mfma_f32_16x16x32_bf16(afl[i], bfh[j], acc[i][j], 0, 0, 0);
            }
        __syncthreads();
    }

    // ---- epilogue: C/D layout col=lane&15, row=(lane>>4)*4+reg (m89)
#pragma unroll
    for (int i = 0; i < 4; ++i) {
#pragma unroll
        for (int j = 0; j < 4; ++j) {
            int col = bn + wn + j * 16 + lr;
            if (col >= OUT) continue;
            float bv = bias ? bias[col] : 0.f;
#pragma unroll
            for (int r = 0; r < 4; ++r) {
                int m = bm + wm + i * 16 + lc * 4 + r;
                if (m >= M) continue;
                float v = acc[i][j][r] + bv;
                if (ACT == 1) v = siluf(v);
                if (OMODE == O_F32) {
                    if (res) v += res[(size_t)m * ldr + col];
                    C[(size_t)m * ldc + col] = v;
                } else if (OMODE == O_F32P) {
                    if (res) v += res[(size_t)m * ldr + col];
                    C[(size_t)m * ldc + col] = v;
                    unsigned short hi = f2bf(v);
                    P1[(size_t)m * ldc + col] = (short)hi;
                    P2[(size_t)m * ldc + col] = (short)f2bf(v - bf2f(hi));
                } else if (OMODE == O_PPE1) {
                    if (col < 256) {
                        unsigned short hi = f2bf(v);
                        P1[(size_t)m * 256 + col] = (short)hi;
                        P2[(size_t)m * 256 + col] = (short)f2bf(v - bf2f(hi));
                    } else {
                        C[(size_t)m * 256 + (col - 256)] = v;
                    }
                } else if (OMODE == O_GATE) {
                    float x2 = res[(size_t)m * ldr + col];
                    float ge = 0.5f * x2 * (1.f + erff(x2 * 0.70710678118654752f));
                    float g = v * ge;
                    unsigned short hi = f2bf(g);
                    P1[(size_t)m * ldc + col] = (short)hi;
                    P2[(size_t)m * ldc + col] = (short)f2bf(g - bf2f(hi));
                } else {  // O_PLANES
                    unsigned short hi = f2bf(v);
                    P1[(size_t)m * ldc + col] = (short)hi;
                    P2[(size_t)m * ldc + col] = (short)f2bf(v - bf2f(hi));
                }
            }
        }
    }
}

// ------------------------- fp32 GEMM (head only) ---------------------------
template <int BM, int BN, int TM, int TN, int ACT>
__launch_bounds__(256) __global__
void gemm_nt(const float* __restrict__ A, int lda,
             const float* __restrict__ W,
             const float* __restrict__ bias,
             const float* __restrict__ res, int ldr,
             float* __restrict__ C, int ldc,
             int M, int K, int OUT)
{
    constexpr int BK = 16;
    __shared__ alignas(16) float As[BK][BM];
    __shared__ alignas(16) float Bs[BK][BN];
    const int tid = threadIdx.x;
    const int bm = blockIdx.x * BM;
    const int bn = blockIdx.y * BN;
    const int tr = (tid >> 4) * TM;
    const int tc = (tid & 15) * TN;

    float acc[TM][TN];
#pragma unroll
    for (int i = 0; i < TM; ++i)
#pragma unroll
        for (int j = 0; j < TN; ++j) acc[i][j] = 0.f;

    for (int k0 = 0; k0 < K; k0 += BK) {
#pragma unroll
        for (int it = 0; it < BM / 64; ++it) {
            int idx = tid + it * 256;
            int m = idx >> 2, kq = idx & 3;
            int gm = bm + m, gk = k0 + kq * 4;
            float t[4] = {0.f, 0.f, 0.f, 0.f};
            if (gm < M) {
#pragma unroll
                for (int j = 0; j < 4; ++j)
                    if (gk + j < K) t[j] = A[(size_t)gm * lda + gk + j];
            }
            As[kq * 4 + 0][m] = t[0];
            As[kq * 4 + 1][m] = t[1];
            As[kq * 4 + 2][m] = t[2];
            As[kq * 4 + 3][m] = t[3];
        }
#pragma unroll
        for (int it = 0; it < BN / 64; ++it) {
            int idx = tid + it * 256;
            int o = idx >> 2, kq = idx & 3;
            int go = bn + o, gk = k0 + kq * 4;
            float t[4] = {0.f, 0.f, 0.f, 0.f};
            if (go < OUT) {
#pragma unroll
                for (int j = 0; j < 4; ++j)
                    if (gk + j < K) t[j] = W[(size_t)go * K + gk + j];
            }
            Bs[kq * 4 + 0][o] = t[0];
            Bs[kq * 4 + 1][o] = t[1];
            Bs[kq * 4 + 2][o] = t[2];
            Bs[kq * 4 + 3][o] = t[3];
        }
        __syncthreads();
#pragma unroll
        for (int kk = 0; kk < BK; ++kk) {
            float a[TM], b[TN];
#pragma unroll
            for (int p = 0; p < TM; ++p) a[p] = As[kk][tr + p];
#pragma unroll
            for (int p = 0; p < TN; ++p) b[p] = Bs[kk][tc + p];
#pragma unroll
            for (int i = 0; i < TM; ++i)
#pragma unroll
                for (int j = 0; j < TN; ++j) acc[i][j] += a[i] * b[j];
        }
        __syncthreads();
    }

#pragma unroll
    for (int i = 0; i < TM; ++i) {
        int m = bm + tr + i;
        if (m >= M) continue;
#pragma unroll
        for (int j = 0; j < TN; ++j) {
            int o = bn + tc + j;
            if (o >= OUT) continue;
            float v = acc[i][j];
            if (bias) v += bias[o];
            if (ACT == 1) v = siluf(v);
            if (res) v += res[(size_t)m * ldr + o];
            C[(size_t)m * ldc + o] = v;
        }
    }
}

// ------------------------- weight prep kernels -----------------------------
__global__ void split_w_k(const float* __restrict__ src, short* __restrict__ dhi,
                          short* __restrict__ dlo, int OUT, int K, int Kp)
{
    int idx = blockIdx.x * blockDim.x + threadIdx.x;
    if (idx >= OUT * Kp) return;
    int row = idx / Kp, col = idx - row * Kp;
    float v = (col < K) ? src[(size_t)row * K + col] : 0.f;
    unsigned short hi = f2bf(v);
    dhi[idx] = (short)hi;
    dlo[idx] = (short)f2bf(v - bf2f(hi));
}

__global__ void stack_qkvs_w_k(const float* __restrict__ Wq, const float* __restrict__ Wk,
                               const float* __restrict__ Wv, const float* __restrict__ Ws,
                               short* __restrict__ dhi, short* __restrict__ dlo, int total)
{
    int idx = blockIdx.x * blockDim.x + threadIdx.x;
    if (idx >= total) return;
    int col = idx & 255;
    int row = (idx >> 8) & 1023;
    int layer = idx >> 18;
    int s2 = row >> 8;
    const float* s = (s2 == 0) ? Wq : ((s2 == 1) ? Wk : ((s2 == 2) ? Wv : Ws));
    float v = s[(size_t)layer * 65536 + (size_t)(row & 255) * 256 + col];
    unsigned short hi = f2bf(v);
    dhi[idx] = (short)hi;
    dlo[idx] = (short)f2bf(v - bf2f(hi));
}

__global__ void stack_qkvs_b_k(const float* __restrict__ bq, const float* __restrict__ bk,
                               const float* __restrict__ bv, const float* __restrict__ bs,
                               float* __restrict__ dst, int total)
{
    int idx = blockIdx.x * blockDim.x + threadIdx.x;
    if (idx >= total) return;
    int r = idx & 1023, layer = idx >> 10;
    int s2 = r >> 8;
    const float* s = (s2 == 0) ? bq : ((s2 == 1) ? bk : ((s2 == 2) ? bv : bs));
    dst[idx] = s[layer * 256 + (r & 255)];
}

// ------------------------- producer kernels (emit planes) -------------------
__global__ void node_prep_k(const float* __restrict__ x,
                            short* __restrict__ fxHi, short* __restrict__ fxLo,
                            short* __restrict__ pxHi, short* __restrict__ pxLo, int n96)
{
    int idx = blockIdx.x * blockDim.x + threadIdx.x;
    if (idx >= n96) return;
    int n = idx / 96, c = idx - n * 96;
    float fv = 0.f, pv = 0.f;
    if (c < 92) {
        float v = x[(size_t)n * 92 + c];
        fv = floorf(v);
        pv = (v - truncf(v)) * 1000.f;
    }
    unsigned short h1 = f2bf(fv);
    fxHi[idx] = (short)h1; fxLo[idx] = (short)f2bf(fv - bf2f(h1));
    unsigned short h2 = f2bf(pv);
    pxHi[idx] = (short)h2; pxLo[idx] = (short)f2bf(pv - bf2f(h2));
}

__global__ void table_rbf_k(short* __restrict__ dhi, short* __restrict__ dlo,
                            int T, float dmin, float step)
{
    int idx = blockIdx.x * blockDim.x + threadIdx.x;   // T*64 threads
    if (idx >= T * 64) return;
    int t = idx >> 6, j4 = (idx & 63) * 4;
    float dv = dmin + step * (float)t;
    short h4[4], l4[4];
#pragma unroll
    for (int j = 0; j < 4; ++j) {
        float c = -6.f + 6.f * (float)(j4 + j) * (1.f / 255.f);
        float u = dv - c;
        float r = expf(-42.5f * u * u);
        unsigned short hi = f2bf(r);
        h4[j] = (short)hi;
        l4[j] = (short)f2bf(r - bf2f(hi));
    }
    *reinterpret_cast<short4*>(dhi + (size_t)t * 256 + j4) = *reinterpret_cast<short4*>(h4);
    *reinterpret_cast<short4*>(dlo + (size_t)t * 256 + j4) = *reinterpret_cast<short4*>(l4);
}

__global__ void edge_prep_k(const float* __restrict__ ea, int* __restrict__ i0,
                            float* __restrict__ fr, int E, float dmin, float invstep, int T)
{
    int i = blockIdx.x * blockDim.x + threadIdx.x;
    if (i < E) {
        float a = ea[(size_t)i * 3], b = ea[(size_t)i * 3 + 1], c = ea[(size_t)i * 3 + 2];
        float d = -1.f / sqrtf(a * a + b * b + c * c);
        float u = (d - dmin) * invstep;
        u = fminf(fmaxf(u, 0.f), (float)(T - 1) - 1e-3f);
        int t0 = (int)u;
        i0[i] = t0;
        fr[i] = u - (float)t0;
    }
}

// ------------------------- edge sort by dst (counting sort) ----------------
__global__ void hist_k(const int* __restrict__ dst, int* __restrict__ deg, int E)
{
    int i = blockIdx.x * blockDim.x + threadIdx.x;
    if (i < E) atomicAdd(&deg[dst[i]], 1);
}

__global__ void scan_k(const int* __restrict__ deg, int* __restrict__ off, int n)
{
    __shared__ int buf[1024];
    __shared__ int carry;
    const int t = threadIdx.x;
    if (t == 0) carry = 0;
    __syncthreads();
    for (int base = 0; base < n; base += 1024) {
        int i = base + t;
        int v = (i < n) ? deg[i] : 0;
        buf[t] = v;
        __syncthreads();
        for (int s = 1; s < 1024; s <<= 1) {
            int add = (t >= s) ? buf[t - s] : 0;
            __syncthreads();
            buf[t] += add;
            __syncthreads();
        }
        if (i < n) off[i] = carry + buf[t] - v;
        __syncthreads();
        if (t == 0) carry += buf[1023];
        __syncthreads();
    }
    if (t == 0) off[n] = carry;
}

__global__ void copy_int_k(const int* __restrict__ a, int* __restrict__ b, int n)
{
    int i = blockIdx.x * blockDim.x + threadIdx.x;
    if (i < n) b[i] = a[i];
}

__global__ void scatter_k(const int* __restrict__ dst, int* __restrict__ cursor,
                          int* __restrict__ esort, int E)
{
    int i = blockIdx.x * blockDim.x + threadIdx.x;
    if (i < E) {
        int p = atomicAdd(&cursor[dst[i]], 1);
        esort[p] = i;
    }
}

// ---- single-pass online-softmax attention, 2-way interleaved + ppe fusion --
// qkvs: [N,1024] fp32 = q|k|v|skip. etab: [T,ldt] fp32 (column slice per layer).
// If ppeb != null: also ppeb += h_new, emit s1 = bn(ppeb) hi/lo planes.
__launch_bounds__(256) __global__
void attn_fused_k(const float* __restrict__ qkvs, const float* __restrict__ etab, int ldt,
                  const int* __restrict__ ei0, const float* __restrict__ efr,
                  const int* __restrict__ src, const int* __restrict__ esort,
                  const int* __restrict__ off, float* __restrict__ hn,
                  float* __restrict__ ppeb, const float* __restrict__ pg,
                  const float* __restrict__ pbeta,
                  short* __restrict__ s1Hi, short* __restrict__ s1Lo, int Nn)
{
    int node = blockIdx.x * 4 + (threadIdx.x >> 6);
    if (node >= Nn) return;
    int lane = threadIdx.x & 63;
    int lo = off[node], hi = off[node + 1];

    const float* qrow = qkvs + (size_t)node * 1024;
    float4 qv = *reinterpret_cast<const float4*>(qrow + lane * 4);
    float4 sk = *reinterpret_cast<const float4*>(qrow + 768 + lane * 4);

    // two independent online-softmax states (exact merge at end)
    float m0 = -3.4e38f, d0 = 0.f, x0 = 0.f, y0 = 0.f, z0 = 0.f, w0 = 0.f;
    float m1 = -3.4e38f, d1 = 0.f, x1 = 0.f, y1 = 0.f, z1 = 0.f, w1 = 0.f;

    for (int jj = lo; jj < hi; jj += 2) {
        bool hasB = (jj + 1 < hi);          // wave-uniform
        int eidA = esort[jj];
        int eidB = esort[hasB ? jj + 1 : jj];
        int spA = src[eidA], spB = src[eidB];
        int tA = ei0[eidA], tB = ei0[eidB];
        float fA = efr[eidA], fB = efr[eidB];
        const float* rA = qkvs + (size_t)spA * 1024;
        const float* rB = qkvs + (size_t)spB * 1024;
        // issue all 8 row loads up front (2 independent chains)
        float4 kA = *reinterpret_cast<const float4*>(rA + 256 + lane * 4);
        float4 vA = *reinterpret_cast<const float4*>(rA + 512 + lane * 4);
        float4 eA0 = *reinterpret_cast<const float4*>(etab + (size_t)tA * ldt + lane * 4);
        float4 eA1 = *reinterpret_cast<const float4*>(etab + (size_t)(tA + 1) * ldt + lane * 4);
        float4 kB = *reinterpret_cast<const float4*>(rB + 256 + lane * 4);
        float4 vB = *reinterpret_cast<const float4*>(rB + 512 + lane * 4);
        float4 eB0 = *reinterpret_cast<const float4*>(etab + (size_t)tB * ldt + lane * 4);
        float4 eB1 = *reinterpret_cast<const float4*>(etab + (size_t)(tB + 1) * ldt + lane * 4);

        float exA0 = eA0.x + fA * (eA1.x - eA0.x);
        float exA1 = eA0.y + fA * (eA1.y - eA0.y);
        float exA2 = eA0.z + fA * (eA1.z - eA0.z);
        float exA3 = eA0.w + fA * (eA1.w - eA0.w);
        float exB0 = eB0.x + fB * (eB1.x - eB0.x);
        float exB1 = eB0.y + fB * (eB1.y - eB0.y);
        float exB2 = eB0.z + fB * (eB1.z - eB0.z);
        float exB3 = eB0.w + fB * (eB1.w - eB0.w);

        float pA = qv.x * (kA.x + exA0) + qv.y * (kA.y + exA1) +
                   qv.z * (kA.z + exA2) + qv.w * (kA.w + exA3);
        float pB = qv.x * (kB.x + exB0) + qv.y * (kB.y + exB1) +
                   qv.z * (kB.z + exB2) + qv.w * (kB.w + exB3);
#pragma unroll
        for (int s = 32; s; s >>= 1) {
            pA += __shfl_xor(pA, s, 64);
            pB += __shfl_xor(pB, s, 64);
        }
        pA *= 0.0625f;
        pB *= 0.0625f;

        float vxA0 = vA.x + exA0, vxA1 = vA.y + exA1, vxA2 = vA.z + exA2, vxA3 = vA.w + exA3;
        if (pA > m0) {
            float sc = expf(m0 - pA);
            d0 = d0 * sc + 1.f;
            x0 = x0 * sc + vxA0; y0 = y0 * sc + vxA1;
            z0 = z0 * sc + vxA2; w0 = w0 * sc + vxA3;
            m0 = pA;
        } else {
            float wg = expf(pA - m0);
            d0 += wg;
            x0 += wg * vxA0; y0 += wg * vxA1; z0 += wg * vxA2; w0 += wg * vxA3;
        }
        if (hasB) {
            float vxB0 = vB.x + exB0, vxB1 = vB.y + exB1, vxB2 = vB.z + exB2, vxB3 = vB.w + exB3;
            if (pB > m1) {
                float sc = expf(m1 - pB);
                d1 = d1 * sc + 1.f;
                x1 = x1 * sc + vxB0; y1 = y1 * sc + vxB1;
                z1 = z1 * sc + vxB2; w1 = w1 * sc + vxB3;
                m1 = pB;
            } else {
                float wg = expf(pB - m1);
                d1 += wg;
                x1 += wg * vxB0; y1 += wg * vxB1; z1 += wg * vxB2; w1 += wg * vxB3;
            }
        }
    }
    // exact merge of the two states
    float mm = fmaxf(m0, m1);
    float sA = (d0 > 0.f) ? expf(m0 - mm) : 0.f;
    float sB = (d1 > 0.f) ? expf(m1 - mm) : 0.f;
    float den = d0 * sA + d1 * sB;
    float ax = x0 * sA + x1 * sB;
    float ay = y0 * sA + y1 * sB;
    float az = z0 * sA + z1 * sB;
    float aw = w0 * sA + w1 * sB;
    float inv = (hi > lo) ? 1.f / den : 0.f;
    float4 o = {sk.x + ax * inv, sk.y + ay * inv, sk.z + az * inv, sk.w + aw * inv};
    *reinterpret_cast<float4*>(hn + (size_t)node * 256 + lane * 4) = o;

    if (ppeb) {   // fused ppe update + BN plane emit (layers 0..2)
        float4 pp = *reinterpret_cast<const float4*>(ppeb + (size_t)node * 256 + lane * 4);
        float4 adj = {pp.x + o.x, pp.y + o.y, pp.z + o.z, pp.w + o.w};
        *reinterpret_cast<float4*>(ppeb + (size_t)node * 256 + lane * 4) = adj;
        float4 g4 = *reinterpret_cast<const float4*>(pg + lane * 4);
        float4 b4 = *reinterpret_cast<const float4*>(pbeta + lane * 4);
        float bn0 = adj.x * g4.x + b4.x;
        float bn1 = adj.y * g4.y + b4.y;
        float bn2 = adj.z * g4.z + b4.z;
        float bn3 = adj.w * g4.w + b4.w;
        unsigned short h0 = f2bf(bn0), h1 = f2bf(bn1), h2 = f2bf(bn2), h3 = f2bf(bn3);
        short4 hs = {(short)h0, (short)h1, (short)h2, (short)h3};
        short4 ls = {(short)f2bf(bn0 - bf2f(h0)), (short)f2bf(bn1 - bf2f(h1)),
                     (short)f2bf(bn2 - bf2f(h2)), (short)f2bf(bn3 - bf2f(h3))};
        *reinterpret_cast<short4*>(s1Hi + (size_t)node * 256 + lane * 4) = hs;
        *reinterpret_cast<short4*>(s1Lo + (size_t)node * 256 + lane * 4) = ls;
    }
}

// ------------------------- pooling / output ---------------------------------
__launch_bounds__(256) __global__
void pool_mean_k(const float* __restrict__ h, const int* __restrict__ batch,
                 float* __restrict__ tot, int Nn)
{
    int g = blockIdx.x;
    __shared__ int sl, sh;
    if (threadIdx.x == 0) {
        int lo = 0, hi = Nn;
        while (lo < hi) { int mid = (lo + hi) >> 1; if (batch[mid] < g) lo = mid + 1; else hi = mid; }
        sl = lo;
        lo = 0; hi = Nn;
        while (lo < hi) { int mid = (lo + hi) >> 1; if (batch[mid] < g + 1) lo = mid + 1; else hi = mid; }
        sh = lo;
    }
    __syncthreads();
    float acc = 0.f;
    for (int n = sl; n < sh; ++n) acc += h[(size_t)n * 256 + threadIdx.x];
    float c = (float)(sh - sl);
    if (c < 1.f) c = 1.f;
    tot[(size_t)g * 256 + threadIdx.x] = acc / c;
}

__launch_bounds__(256) __global__
void out_k(const float* __restrict__ crystal, const float* __restrict__ oW,
           const float* __restrict__ ob, const float* __restrict__ nosda,
           float* __restrict__ out, int Bn)
{
    int b = blockIdx.x;
    __shared__ float red[256];
    float p = crystal[(size_t)b * 256 + threadIdx.x] * oW[threadIdx.x];
    red[threadIdx.x] = p;
    __syncthreads();
    for (int s = 128; s; s >>= 1) {
        if (threadIdx.x < s) red[threadIdx.x] += red[threadIdx.x + s];
        __syncthreads();
    }
    if (threadIdx.x == 0) out[b] = (red[0] + ob[0]) / nosda[b];
}

// ---------------------------------------------------------------------------
extern "C" void kernel_launch(void* const* d_in, const int* in_sizes, int n_in,
                              void* d_out, int out_size, void* d_ws, size_t ws_size,
                              hipStream_t stream)
{
    const float* x     = (const float*)d_in[0];
    const int*   ei    = (const int*)d_in[1];
    const float* ea    = (const float*)d_in[2];
    const int*   batch = (const int*)d_in[3];
    const float* nosda = (const float*)d_in[4];
    const float* ae_W1 = (const float*)d_in[5];
    const float* ae_b1 = (const float*)d_in[6];
    const float* ae_W2 = (const float*)d_in[7];
    const float* ae_b2 = (const float*)d_in[8];
    const float* ee_W  = (const float*)d_in[9];
    const float* ee_b  = (const float*)d_in[10];
    const float* pe_W  = (const float*)d_in[11];
    const float* pe_b  = (const float*)d_in[12];
    const float* Wq    = (const float*)d_in[13];
    const float* bq    = (const float*)d_in[14];
    const float* Wk    = (const float*)d_in[15];
    const float* bk    = (const float*)d_in[16];
    const float* Wv    = (const float*)d_in[17];
    const float* bv    = (const float*)d_in[18];
    const float* We    = (const float*)d_in[19];
    const float* be    = (const float*)d_in[20];
    const float* Ws    = (const float*)d_in[21];
    const float* bs    = (const float*)d_in[22];
    const float* pW1   = (const float*)d_in[23];
    const float* pb1   = (const float*)d_in[24];
    const float* pW2   = (const float*)d_in[25];
    const float* pb2   = (const float*)d_in[26];
    const float* pW3   = (const float*)d_in[27];
    const float* pb3   = (const float*)d_in[28];
    const float* pg    = (const float*)d_in[29];
    const float* pbeta = (const float*)d_in[30];
    const float* fc_W  = (const float*)d_in[31];
    const float* fc_b  = (const float*)d_in[32];
    const float* out_W = (const float*)d_in[33];
    const float* out_b = (const float*)d_in[34];

    const int CG = 92, F = 256;
    const int N = in_sizes[0] / CG;
    const int E = in_sizes[1] / 2;
    const int B = in_sizes[4];
    const int T = 4096;
    const float DMIN = -8.f, DMAX = 0.f;
    const float STEP = (DMAX - DMIN) / (float)(T - 1);
    const int* src  = ei;
    const int* dstp = ei + E;

    // ---- workspace carve-up (~214 MB; proven-safe budget ~256 MB) ----------
    float* w = (float*)d_ws;
    auto take = [&](size_t n) { float* p = w; w += n; return p; };
    auto takeS = [&](size_t nshorts) { short* p = (short*)w; w += (nshorts + 1) / 2; return p; };
    const size_t NF = (size_t)N * F;
    float* hb0  = take(NF);
    float* hb1  = take(NF);
    float* ppeb = take(NF);
    short* hHi  = takeS(NF);           // planes of current h (qkvs GEMM input)
    short* hLo  = takeS(NF);
    short* s1Hi = takeS(NF);           // bn planes (p1 GEMM input)
    short* s1Lo = takeS(NF);
    float* etab = take((size_t)4 * T * F);     // fp32 e-tables [T,1024] stacked
    float* arena = take((size_t)N * 1024);     // time-shared (T1/T2/T3)
    float* efr  = take(E);
    float* totb = take((size_t)B * F);
    float* cryb = take((size_t)B * F);
    float* bstk = take(4 * 1024);
    // weight planes
    short* qwHi = takeS((size_t)4 * 1024 * 256);
    short* qwLo = takeS((size_t)4 * 1024 * 256);
    short* eeHi = takeS((size_t)256 * 256);
    short* eeLo = takeS((size_t)256 * 256);
    short* weHi = takeS((size_t)4 * 256 * 256);   // [1024,256] stacked
    short* weLo = takeS((size_t)4 * 256 * 256);
    short* a1Hi = takeS((size_t)256 * 96);
    short* a1Lo = takeS((size_t)256 * 96);
    short* a2Hi = takeS((size_t)256 * 256);
    short* a2Lo = takeS((size_t)256 * 256);
    short* peHi = takeS((size_t)256 * 96);
    short* peLo = takeS((size_t)256 * 96);
    short* p1Hi = takeS((size_t)3 * 512 * 256);
    short* p1Lo = takeS((size_t)3 * 512 * 256);
    short* p2Hi = takeS((size_t)3 * 256 * 256);
    short* p2Lo = takeS((size_t)3 * 256 * 256);
    short* p3Hi = takeS((size_t)3 * 256 * 256);
    short* p3Lo = takeS((size_t)3 * 256 * 256);
    int* ei0    = (int*)w; w += E;
    int* deg    = (int*)w; w += N;
    int* offb   = (int*)w; w += (N + 1);
    int* curb   = (int*)w; w += N;
    int* esort  = (int*)w; w += E;
    size_t need = (size_t)((char*)w - (char*)d_ws);
    if (need > ws_size) return;               // fail loud, not a fault
    (void)n_in; (void)out_size;

    // Arena tenants (disjoint lifetimes):
    // T1 (pre-loop): fx/px planes [N,96], rb/ef planes [T,256], emb planes [N,256]
    short* fxHi = (short*)arena;
    short* fxLo = fxHi + (size_t)N * 96;
    short* pxHi = fxLo + (size_t)N * 96;
    short* pxLo = pxHi + (size_t)N * 96;
    short* rbHi = pxLo + (size_t)N * 96;
    short* rbLo = rbHi + (size_t)T * 256;
    short* efHi = rbLo + (size_t)T * 256;
    short* efLo = efHi + (size_t)T * 256;
    short* embHi = efLo + (size_t)T * 256;
    short* embLo = embHi + NF;
    // T2 (attn phase): qkvs fp32 [N,1024] = whole arena
    float* qkvs = arena;
    // T3 (ppe phase): a2b1 planes + x2b fp32 + s3 planes (3*NF floats total)
    short* a2b1Hi = (short*)arena;
    short* a2b1Lo = a2b1Hi + NF;
    float* x2b = arena + NF;
    short* s3Hi = (short*)(arena + 2 * NF);
    short* s3Lo = s3Hi + NF;

    dim3 blk(256);
    auto g1 = [](int n) { return dim3((n + 255) / 256); };

    // ---- prep + weight splitting
    node_prep_k<<<g1(N * 96), blk, 0, stream>>>(x, fxHi, fxLo, pxHi, pxLo, N * 96);
    edge_prep_k<<<g1(E), blk, 0, stream>>>(ea, ei0, efr, E, DMIN, 1.f / STEP, T);
    table_rbf_k<<<g1(T * 64), blk, 0, stream>>>(rbHi, rbLo, T, DMIN, STEP);

    stack_qkvs_w_k<<<g1(4 * 1024 * 256), blk, 0, stream>>>(Wq, Wk, Wv, Ws, qwHi, qwLo, 4 * 1024 * 256);
    stack_qkvs_b_k<<<g1(4 * 1024), blk, 0, stream>>>(bq, bk, bv, bs, bstk, 4 * 1024);
    split_w_k<<<g1(256 * 256), blk, 0, stream>>>(ee_W, eeHi, eeLo, 256, 256, 256);
    split_w_k<<<g1(4 * 256 * 256), blk, 0, stream>>>(We, weHi, weLo, 1024, 256, 256);
    split_w_k<<<g1(256 * 96), blk, 0, stream>>>(ae_W1, a1Hi, a1Lo, 256, 92, 96);
    split_w_k<<<g1(256 * 256), blk, 0, stream>>>(ae_W2, a2Hi, a2Lo, 256, 256, 256);
    split_w_k<<<g1(256 * 96), blk, 0, stream>>>(pe_W, peHi, peLo, 256, 92, 96);
    split_w_k<<<g1(3 * 512 * 256), blk, 0, stream>>>(pW1, p1Hi, p1Lo, 1536, 256, 256);
    split_w_k<<<g1(3 * 256 * 256), blk, 0, stream>>>(pW2, p2Hi, p2Lo, 768, 256, 256);
    split_w_k<<<g1(3 * 256 * 256), blk, 0, stream>>>(pW3, p3Hi, p3Lo, 768, 256, 256);

    // ---- tables: ef = silu(rbf@eeW) (planes); etab = ef@[We0..We3]^T stacked
    {
        dim3 grid((T + 127) / 128, 2);
        gemm_spp<1, O_PLANES><<<grid, blk, 0, stream>>>(rbHi, rbLo, 256, eeHi, eeLo, 256,
                                                        ee_b, nullptr, 0, nullptr, efHi, efLo, 256, T, 256, 256);
    }
    {
        dim3 grid((T + 127) / 128, 8);   // one OUT=1024 launch, etab [T,1024]
        gemm_spp<0, O_F32><<<grid, blk, 0, stream>>>(efHi, efLo, 256, weHi, weLo, 256,
                                                     be, nullptr, 0, etab, nullptr, nullptr, 1024, T, 1024, 256);
    }

    // ---- embeddings
    {
        dim3 grid((N + 127) / 128, 2);
        gemm_spp<1, O_PLANES><<<grid, blk, 0, stream>>>(fxHi, fxLo, 96, a1Hi, a1Lo, 96,
                                                        ae_b1, nullptr, 0, nullptr, embHi, embLo, 256, N, 256, 96);
        gemm_spp<0, O_F32P><<<grid, blk, 0, stream>>>(embHi, embLo, 256, a2Hi, a2Lo, 256,
                                                      ae_b2, nullptr, 0, hb0, hHi, hLo, 256, N, 256, 256);
        gemm_spp<0, O_F32><<<grid, blk, 0, stream>>>(pxHi, pxLo, 96, peHi, peLo, 96,
                                                     pe_b, nullptr, 0, ppeb, nullptr, nullptr, 256, N, 256, 96);
    }

    // ---- counting-sort edges by dst
    hipMemsetAsync(deg, 0, (size_t)N * sizeof(int), stream);
    hist_k<<<g1(E), blk, 0, stream>>>(dstp, deg, E);
    scan_k<<<1, 1024, 0, stream>>>(deg, offb, N);
    copy_int_k<<<g1(N), blk, 0, stream>>>(offb, curb, N);
    scatter_k<<<g1(E), blk, 0, stream>>>(dstp, curb, esort, E);

    float* h  = hb0;
    float* hn = hb1;
    for (int i = 0; i < 4; ++i) {
        // fused q|k|v|skip GEMM from h planes -> qkvs fp32 [N,1024]  (T2)
        {
            dim3 grid((N + 127) / 128, 8);
            gemm_spp<0, O_F32><<<grid, blk, 0, stream>>>(hHi, hLo, 256,
                qwHi + (size_t)i * 262144, qwLo + (size_t)i * 262144, 256,
                bstk + (size_t)i * 1024, nullptr, 0, qkvs, nullptr, nullptr, 1024, N, 1024, 256);
        }

        // attention (+ fused ppe update for layers 0..2)
        if (i < 3) {
            attn_fused_k<<<dim3((N + 3) / 4), blk, 0, stream>>>(
                qkvs, etab + (size_t)i * 256, 1024, ei0, efr, src, esort, offb, hn,
                ppeb, pg + (size_t)i * F, pbeta + (size_t)i * F, s1Hi, s1Lo, N);
        } else {
            attn_fused_k<<<dim3((N + 3) / 4), blk, 0, stream>>>(
                qkvs, etab + (size_t)i * 256, 1024, ei0, efr, src, esort, offb, hn,
                nullptr, nullptr, nullptr, nullptr, nullptr, N);
        }
        { float* t = h; h = hn; hn = t; }

        if (i < 3) {                                     // ppe phase (T3)
            {
                dim3 grid((N + 127) / 128, 4);
                gemm_spp<0, O_PPE1><<<grid, blk, 0, stream>>>(s1Hi, s1Lo, 256,
                    p1Hi + (size_t)i * 131072, p1Lo + (size_t)i * 131072, 256,
                    pb1 + (size_t)i * 512, nullptr, 0, x2b, a2b1Hi, a2b1Lo, 0, N, 512, 256);
            }
            {   // p2 with fused gate: s3 = x1 * gelu(x2b)
                dim3 grid((N + 127) / 128, 2);
                gemm_spp<0, O_GATE><<<grid, blk, 0, stream>>>(a2b1Hi, a2b1Lo, 256,
                    p2Hi + (size_t)i * 65536, p2Lo + (size_t)i * 65536, 256,
                    pb2 + (size_t)i * F, x2b, 256, nullptr, s3Hi, s3Lo, 256, N, 256, 256);
            }
            {
                dim3 grid((N + 127) / 128, 2);
                gemm_spp<0, O_F32P><<<grid, blk, 0, stream>>>(s3Hi, s3Lo, 256,
                    p3Hi + (size_t)i * 65536, p3Lo + (size_t)i * 65536, 256,
                    pb3 + (size_t)i * F, h, 256, hn, hHi, hLo, 256, N, 256, 256);
            }
            { float* t = h; h = hn; hn = t; }
        }
    }

    // ---- pooling + head (fp32)
    pool_mean_k<<<dim3(B), blk, 0, stream>>>(h, batch, totb, N);
    {
        dim3 grid((B + 63) / 64, (F + 63) / 64);
        gemm_nt<64, 64, 4, 4, 1><<<grid, blk, 0, stream>>>(totb, F, fc_W, fc_b, totb, F, cryb, F, B, F, F);
    }
    out_k<<<dim3(B), blk, 0, stream>>>(cryb, out_W, out_b, nosda, (float*)d_out, B);
}